// Round 6
// baseline (1417.253 us; speedup 1.0000x reference)
//
#include <hip/hip_runtime.h>

typedef __attribute__((ext_vector_type(4))) float f32x4;
typedef __attribute__((ext_vector_type(16))) float f32x16;
typedef __attribute__((ext_vector_type(8))) short short8;
typedef __attribute__((ext_vector_type(4))) unsigned short ushort4v;

__device__ __forceinline__ unsigned short rne_bf16(float f) {
  unsigned int u = __builtin_bit_cast(unsigned int, f);
  u += 0x7FFFu + ((u >> 16) & 1u);
  return (unsigned short)(u >> 16);
}

__device__ __forceinline__ void async16(void* lds, const void* g) {
  __builtin_amdgcn_global_load_lds(
      (const __attribute__((address_space(1))) void*)g,
      (__attribute__((address_space(3))) void*)lds, 16, 0, 0);
}

__device__ __forceinline__ f32x4 mfma16(short8 a, short8 b, f32x4 c) {
  return __builtin_amdgcn_mfma_f32_16x16x32_bf16(a, b, c, 0, 0, 0);
}
__device__ __forceinline__ f32x16 mfma32(short8 a, short8 b, f32x16 c) {
  return __builtin_amdgcn_mfma_f32_32x32x16_bf16(a, b, c, 0, 0, 0);
}

// ---------------- f32 -> bf16 cast (vectorized, grid-stride) ----------------
__global__ __launch_bounds__(256) void cast_k(const float* __restrict__ in,
                                              unsigned short* __restrict__ out,
                                              int n4) {
  int stride = gridDim.x * 256;
  for (int i = blockIdx.x * 256 + threadIdx.x; i < n4; i += stride) {
    float4 v = ((const float4*)in)[i];
    ushort4v o = {rne_bf16(v.x), rne_bf16(v.y), rne_bf16(v.z), rne_bf16(v.w)};
    ((ushort4v*)out)[i] = o;
  }
}

// ============ 256x256-tile GEMM, 32x32x16 MFMA: C = A @ B^T ==================
// 8 waves (2M x 4N), per-wave 128x64 = 4x2 frags of 32x32. LDS/staging/rotation
// IDENTICAL to the R4/R5-proven ledger: 4 rotating 32KB regions, region Q =
// (tile Q>>1, kh Q&1) at ((Q>>1)&1)*32768 + (Q&1)*8192 (A; B +16384); phase P
// stages region P+3, gate vmcnt(4) (vmcnt(0) when no stage), 1 barrier/phase.
// Stored chunk swizzle (from staging): stored[row][ch] = global chunk
// ch ^ ((row>>1)&3). 32x32 A-frag read: lane l, frag f, kstep ks: row =
// wm*128+f*32+(l&31), global chunk = ks*2+(l>>5) -> LDS chunk ^= ((l&31)>>1)&3.
// Balanced across banks (8 lanes per 16B slot in each 128B window = optimal).
// MODE 0: QKV proj -> bf16 head-transposed dst[(b*16+h)][i][tok], *scale
// MODE 3: out proj -> f32 outF[m*4096+n] + bias[n]
template <int MODE>
__global__ __launch_bounds__(512, 2) void gemm256(const unsigned short* __restrict__ A,
                                                  const unsigned short* __restrict__ B,
                                                  float* __restrict__ outF,
                                                  unsigned short* __restrict__ outB,
                                                  const float* __restrict__ bias,
                                                  int K, int lda, int ldb,
                                                  float scale, int gx) {
  __shared__ unsigned short lds[65536];  // 128 KiB
  const int tid = threadIdx.x;
  const int lane = tid & 63;
  const int wid = tid >> 6;
  const int wm = wid >> 2;  // 0..1 -> 128 rows
  const int wn = wid & 3;   // 0..3 -> 64 cols
  int lin = blockIdx.x;
  lin = (lin & 7) * (gridDim.x >> 3) + (lin >> 3);  // XCD swizzle (grid%8==0)
  const int bx = lin % gx;
  const int by = lin / gx;
  const int m0 = by * 256, n0 = bx * 256;
  const int NT = K >> 6;

  // staging: thread t covers LDS slot p = tid (+512): row=p>>2, chunk=p&3
  const int gsw8 = (((tid & 3) ^ ((tid >> 3) & 3))) * 8;  // pre-swizzled col
  const unsigned short* gA = A + (size_t)(m0 + (tid >> 2)) * lda + gsw8;
  const unsigned short* gB = B + (size_t)(n0 + (tid >> 2)) * ldb + gsw8;
  const size_t astep = (size_t)128 * lda;
  const size_t bstep = (size_t)128 * ldb;
  unsigned short* ld0 = &lds[tid * 8];

#define STG_A(Q) do { \
    const int kt_ = ((Q) >> 1) * 64 + ((Q) & 1) * 32; \
    const int off_ = (((Q) >> 1) & 1) * 32768 + ((Q) & 1) * 8192; \
    const unsigned short* sA_ = gA + kt_; \
    unsigned short* dA_ = ld0 + off_; \
    async16(dA_, sA_); async16(dA_ + 4096, sA_ + astep); } while (0)
#define STG_B(Q) do { \
    const int kt_ = ((Q) >> 1) * 64 + ((Q) & 1) * 32; \
    const int off_ = 16384 + (((Q) >> 1) & 1) * 32768 + ((Q) & 1) * 8192; \
    const unsigned short* sB_ = gB + kt_; \
    unsigned short* dB_ = ld0 + off_; \
    async16(dB_, sB_); async16(dB_ + 4096, sB_ + bstep); } while (0)

  // 32x32 fragment read addresses (shorts, + region base)
  const int l31 = lane & 31;
  const int hi = lane >> 5;
  const int q4 = (l31 >> 1) & 3;
  const int co0 = ((hi) ^ q4) * 8;        // ks=0: global chunk hi
  const int co1 = ((2 + hi) ^ q4) * 8;    // ks=1: global chunk 2+hi
  const int abase = (wm * 128 + l31) * 32;
  const int bbase = 16384 + (wn * 64 + l31) * 32;

  short8 af[8], bf[4];
#define READ12(base) do { \
    _Pragma("unroll") \
    for (int f_ = 0; f_ < 4; ++f_) { \
      af[f_]     = *(const short8*)&lds[(base) + abase + f_ * 1024 + co0]; \
      af[4 + f_] = *(const short8*)&lds[(base) + abase + f_ * 1024 + co1]; \
    } \
    bf[0] = *(const short8*)&lds[(base) + bbase + co0]; \
    bf[1] = *(const short8*)&lds[(base) + bbase + 1024 + co0]; \
    bf[2] = *(const short8*)&lds[(base) + bbase + co1]; \
    bf[3] = *(const short8*)&lds[(base) + bbase + 1024 + co1]; \
  } while (0)

  f32x16 acc[4][2];
#pragma unroll
  for (int f = 0; f < 4; ++f)
#pragma unroll
    for (int g = 0; g < 2; ++g)
#pragma unroll
      for (int e = 0; e < 16; ++e) acc[f][g][e] = 0.f;

#define MFMA16() do { \
    __builtin_amdgcn_s_setprio(1); \
    _Pragma("unroll") \
    for (int f_ = 0; f_ < 4; ++f_) \
      _Pragma("unroll") \
      for (int g_ = 0; g_ < 2; ++g_) \
        acc[f_][g_] = mfma32(af[f_], bf[g_], acc[f_][g_]); \
    _Pragma("unroll") \
    for (int f_ = 0; f_ < 4; ++f_) \
      _Pragma("unroll") \
      for (int g_ = 0; g_ < 2; ++g_) \
        acc[f_][g_] = mfma32(af[4 + f_], bf[2 + g_], acc[f_][g_]); \
    __builtin_amdgcn_s_setprio(0); \
  } while (0)

  // ---- prologue: stage regions 0,1,2; retire 0,1 (region 2 in flight)
  STG_A(0); STG_B(0); STG_A(1); STG_B(1); STG_A(2); STG_B(2);
  asm volatile("s_waitcnt vmcnt(4)" ::: "memory");
  __builtin_amdgcn_s_barrier();

  const int PMAX = 2 * NT - 1;
  for (int t = 0; t < NT; ++t) {
    const int bb = (t & 1) * 32768;
    {  // phase P = 2t (kh0)
      READ12(bb);
      const bool st = (2 * t + 3) <= PMAX;
      if (st) { STG_A(2 * t + 3); STG_B(2 * t + 3); }
      MFMA16();
      if (st) asm volatile("s_waitcnt vmcnt(4)" ::: "memory");
      else    asm volatile("s_waitcnt vmcnt(0)" ::: "memory");
      __builtin_amdgcn_s_barrier();
    }
    {  // phase P = 2t+1 (kh1)
      READ12(bb + 8192);
      const bool st = (2 * t + 4) <= PMAX;
      if (st) { STG_A(2 * t + 4); STG_B(2 * t + 4); }
      MFMA16();
      if (st) asm volatile("s_waitcnt vmcnt(4)" ::: "memory");
      else    asm volatile("s_waitcnt vmcnt(0)" ::: "memory");
      __builtin_amdgcn_s_barrier();
    }
  }
#undef STG_A
#undef STG_B
#undef READ12
#undef MFMA16

  // ---- epilogue: 32x32 C frag: col = lane&31, row = (q&3)+8*(q>>2)+4*hi
#pragma unroll
  for (int f = 0; f < 4; ++f) {
#pragma unroll
    for (int g = 0; g < 2; ++g) {
      f32x16 v = acc[f][g];
      const int mb = m0 + wm * 128 + f * 32;
      const int n = n0 + wn * 64 + g * 32 + l31;
      if (MODE == 0) {
        const size_t hb = ((size_t)((m0 >> 8) * 16 + (n >> 8))) * 65536 +
                          (size_t)(n & 255) * 256;
#pragma unroll
        for (int qq = 0; qq < 4; ++qq) {
          ushort4v p;
#pragma unroll
          for (int j = 0; j < 4; ++j) p[j] = rne_bf16(v[qq * 4 + j] * scale);
          const int tok = (mb & 255) + qq * 8 + hi * 4;
          *(ushort4v*)&outB[hb + tok] = p;
        }
      } else {
        const float bv = bias[n];
#pragma unroll
        for (int qq = 0; qq < 4; ++qq)
#pragma unroll
          for (int j = 0; j < 4; ++j) {
            const int m = mb + qq * 8 + hi * 4 + j;
            outF[(size_t)m * 4096 + n] = v[qq * 4 + j] + bv;
          }
      }
    }
  }
}

// ============ fused S = Qt @ Kt^T + row-softmax (per head) ===================
// Block: 128 rows x 256 cols of S for one head; 4 waves (2M x 2N).
// K-loop: simple 2-barrier gload_lds staging (K=256, BK=32).
// Epilogue: cross-wave row max/sum via LDS, write P f32 to outA (attn output)
// and P bf16 to Pb (PV input). Saves the S f32 round-trip + softmax pass.
__global__ __launch_bounds__(256) void sgemm_sm(const unsigned short* __restrict__ Qt,
                                                const unsigned short* __restrict__ Kt,
                                                float* __restrict__ outA,
                                                unsigned short* __restrict__ Pb) {
  __shared__ short Ash[128 * 32];
  __shared__ short Bsh[256 * 32];
  __shared__ float redM[128][2];
  __shared__ float redS[128][2];

  const int tid = threadIdx.x;
  const int lane = tid & 63;
  const int wid = tid >> 6;
  const int z = blockIdx.y;
  const int m0 = blockIdx.x * 128;
  const int wm = wid >> 1;   // 0..1 -> 64 rows
  const int wn = wid & 1;    // 0..1 -> 128 cols
  const int fcol = lane & 15;
  const int kslot = (lane >> 4) * 8;
  const int frow = (lane >> 4) * 4;

  const unsigned short* Ah = Qt + (size_t)z * 65536;
  const unsigned short* Bh = Kt + (size_t)z * 65536;

  f32x4 acc[4][8];
#pragma unroll
  for (int r = 0; r < 4; ++r)
#pragma unroll
    for (int s = 0; s < 8; ++s) acc[r][s] = (f32x4){0.f, 0.f, 0.f, 0.f};

  const int arow = tid >> 2;
  const int acol = (tid & 3) * 8;
  const unsigned short* gA = Ah + (size_t)(m0 + arow) * 256 + acol;
  const unsigned short* gB = Bh + (size_t)arow * 256 + acol;
  short* lA = &Ash[tid * 8];
  short* lB = &Bsh[tid * 8];

  for (int kt = 0; kt < 256; kt += 32) {
    __syncthreads();
    async16(lA, gA + kt);
    async16(lA + 2048, gA + (size_t)64 * 256 + kt);
    async16(lB, gB + kt);
    async16(lB + 2048, gB + (size_t)64 * 256 + kt);
    async16(lB + 4096, gB + (size_t)128 * 256 + kt);
    async16(lB + 6144, gB + (size_t)192 * 256 + kt);
    __syncthreads();

    short8 a[4], b[8];
#pragma unroll
    for (int r = 0; r < 4; ++r)
      a[r] = *(const short8*)&Ash[(wm * 64 + r * 16 + fcol) * 32 + kslot];
#pragma unroll
    for (int s = 0; s < 8; ++s)
      b[s] = *(const short8*)&Bsh[(wn * 128 + s * 16 + fcol) * 32 + kslot];
#pragma unroll
    for (int r = 0; r < 4; ++r)
#pragma unroll
      for (int s = 0; s < 8; ++s)
        acc[r][s] = mfma16(a[r], b[s], acc[r][s]);
  }
  __syncthreads();  // LDS reads done; safe to repurpose nothing, just sync

  // ---- row max (over this wave's 128 cols), combine 2 wn-waves via LDS
#pragma unroll
  for (int r = 0; r < 4; ++r) {
#pragma unroll
    for (int j = 0; j < 4; ++j) {
      float m = acc[r][0][j];
#pragma unroll
      for (int s = 1; s < 8; ++s) m = fmaxf(m, acc[r][s][j]);
#pragma unroll
      for (int off = 1; off < 16; off <<= 1) m = fmaxf(m, __shfl_xor(m, off, 64));
      if (fcol == 0) redM[wm * 64 + r * 16 + frow + j][wn] = m;
    }
  }
  __syncthreads();
  // ---- exp + row sum
#pragma unroll
  for (int r = 0; r < 4; ++r) {
#pragma unroll
    for (int j = 0; j < 4; ++j) {
      const int rl = wm * 64 + r * 16 + frow + j;
      const float m = fmaxf(redM[rl][0], redM[rl][1]);
      float sum = 0.f;
#pragma unroll
      for (int s = 0; s < 8; ++s) {
        float e = __expf(acc[r][s][j] - m);
        acc[r][s][j] = e;
        sum += e;
      }
#pragma unroll
      for (int off = 1; off < 16; off <<= 1) sum += __shfl_xor(sum, off, 64);
      if (fcol == 0) redS[rl][wn] = sum;
    }
  }
  __syncthreads();
  // ---- normalize + write f32 (attn out) and bf16 (PV input)
#pragma unroll
  for (int r = 0; r < 4; ++r) {
#pragma unroll
    for (int j = 0; j < 4; ++j) {
      const int rl = wm * 64 + r * 16 + frow + j;
      const float inv = 1.0f / (redS[rl][0] + redS[rl][1]);
      const size_t rowo = (size_t)z * 65536 + (size_t)(m0 + rl) * 256;
#pragma unroll
      for (int s = 0; s < 8; ++s) {
        const float p = acc[r][s][j] * inv;
        const size_t o = rowo + wn * 128 + s * 16 + fcol;
        outA[o] = p;
        Pb[o] = rne_bf16(p);
      }
    }
  }
}

// ---------------- 128x128 GEMM for PV ---------------------------------------
// MODE 2: PV (batched by z) -> bf16 out_x[((z>>4)*256+m)*4096+(z&15)*256+n]
template <int MODE>
__global__ __launch_bounds__(256) void gemm_bt(const unsigned short* __restrict__ Ab,
                                               const unsigned short* __restrict__ Bb,
                                               float* __restrict__ outF,
                                               unsigned short* __restrict__ outB,
                                               int K, int lda, int ldb) {
  __shared__ short Ash[128 * 32];
  __shared__ short Bsh[128 * 32];

  const int tid = threadIdx.x;
  const int lane = tid & 63;
  const int wid = tid >> 6;
  const int z = blockIdx.z;
  const int m0 = blockIdx.y * 128;
  const int n0 = blockIdx.x * 128;

  const unsigned short* A = Ab + (size_t)z * 65536;
  const unsigned short* B = Bb + (size_t)z * 65536;

  const int wm = (wid >> 1) * 64;
  const int wn = (wid & 1) * 64;
  const int fcol = lane & 15;
  const int kslot = (lane >> 4) * 8;

  f32x4 acc[4][4];
#pragma unroll
  for (int r = 0; r < 4; ++r)
#pragma unroll
    for (int s = 0; s < 4; ++s) acc[r][s] = (f32x4){0.f, 0.f, 0.f, 0.f};

  const int arow = tid >> 2;
  const int acol = (tid & 3) * 8;
  const unsigned short* gA = A + (size_t)(m0 + arow) * lda + acol;
  const unsigned short* gB = B + (size_t)(n0 + arow) * ldb + acol;
  short* lA = &Ash[tid * 8];
  short* lB = &Bsh[tid * 8];

  for (int kt = 0; kt < K; kt += 32) {
    __syncthreads();
    async16(lA, gA + kt);
    async16(lA + 2048, gA + (size_t)64 * lda + kt);
    async16(lB, gB + kt);
    async16(lB + 2048, gB + (size_t)64 * ldb + kt);
    __syncthreads();

    short8 a[4], b[4];
#pragma unroll
    for (int r = 0; r < 4; ++r)
      a[r] = *(const short8*)&Ash[(wm + r * 16 + fcol) * 32 + kslot];
#pragma unroll
    for (int s = 0; s < 4; ++s)
      b[s] = *(const short8*)&Bsh[(wn + s * 16 + fcol) * 32 + kslot];
#pragma unroll
    for (int r = 0; r < 4; ++r)
#pragma unroll
      for (int s = 0; s < 4; ++s)
        acc[r][s] = mfma16(a[r], b[s], acc[r][s]);
  }

  const int frow = (lane >> 4) * 4;
#pragma unroll
  for (int r = 0; r < 4; ++r) {
#pragma unroll
    for (int s = 0; s < 4; ++s) {
      f32x4 v = acc[r][s];
      const int m = m0 + wm + r * 16 + frow;
      const int n = n0 + wn + s * 16 + fcol;
      size_t base = ((size_t)((z >> 4) * 256 + m)) * 4096 + (z & 15) * 256 + n;
#pragma unroll
      for (int j = 0; j < 4; ++j) outB[base + (size_t)j * 4096] = rne_bf16(v[j]);
    }
  }
}

// -----------------------------------------------------------------------------
extern "C" void kernel_launch(void* const* d_in, const int* in_sizes, int n_in,
                              void* d_out, int out_size, void* d_ws, size_t ws_size,
                              hipStream_t stream) {
  const float* x1 = (const float*)d_in[0];
  const float* x2 = (const float*)d_in[1];
  const float* Wq = (const float*)d_in[2];
  const float* Wk = (const float*)d_in[3];
  const float* Wv = (const float*)d_in[4];
  const float* Wp = (const float*)d_in[5];
  const float* bp = (const float*)d_in[6];

  float* outX = (float*)d_out;                   // x: [8192,4096] f32
  float* outA = outX + (size_t)33554432;         // attn: [512,256,256] f32

  unsigned short* Qt  = (unsigned short*)d_ws;   // [512][256][256] head-transposed
  unsigned short* Kt  = Qt + 33554432;
  unsigned short* Vt  = Kt + 33554432;
  unsigned short* x1b = Vt + 33554432;           // x1 bf16; later P bf16
  unsigned short* x2b = x1b + 33554432;          // x2 bf16; later out_x bf16
  unsigned short* Wb  = x2b + 33554432;          // current weight bf16 [4096,4096]

  const float SCALE = 0.0625f;  // 256^-0.5

  cast_k<<<2048, 256, 0, stream>>>(x1, x1b, 8388608);
  cast_k<<<2048, 256, 0, stream>>>(x2, x2b, 8388608);

  // Q = (x1 @ Wq^T) * SCALE -> Qt[b,h,i,tok]
  cast_k<<<2048, 256, 0, stream>>>(Wq, Wb, 4194304);
  gemm256<0><<<512, 512, 0, stream>>>(x1b, Wb, nullptr, Qt, nullptr,
                                      4096, 4096, 4096, SCALE, 16);
  // K = x2 @ Wk^T -> Kt
  cast_k<<<2048, 256, 0, stream>>>(Wk, Wb, 4194304);
  gemm256<0><<<512, 512, 0, stream>>>(x2b, Wb, nullptr, Kt, nullptr,
                                      4096, 4096, 4096, 1.0f, 16);
  // V = x2 @ Wv^T -> Vt
  cast_k<<<2048, 256, 0, stream>>>(Wv, Wb, 4194304);
  gemm256<0><<<512, 512, 0, stream>>>(x2b, Wb, nullptr, Vt, nullptr,
                                      4096, 4096, 4096, 1.0f, 16);

  // S = Qt @ Kt^T per head, fused row-softmax -> outA f32 + x1b bf16
  sgemm_sm<<<dim3(2, 512), 256, 0, stream>>>(Qt, Kt, outA, x1b);
  // out = P @ Vt^T per head -> bf16 x-layout into x2b
  gemm_bt<2><<<dim3(2, 2, 512), 256, 0, stream>>>(x1b, Vt, nullptr, x2b, 256, 256, 256);

  // x = out @ Wp^T + bp -> d_out
  cast_k<<<2048, 256, 0, stream>>>(Wp, Wb, 4194304);
  gemm256<3><<<512, 512, 0, stream>>>(x2b, Wb, outX, nullptr, bp,
                                      4096, 4096, 4096, 1.0f, 16);
}

// Round 7
// 1264.249 us; speedup vs baseline: 1.1210x; 1.1210x over previous
//
#include <hip/hip_runtime.h>

typedef __attribute__((ext_vector_type(4))) float f32x4;
typedef __attribute__((ext_vector_type(8))) short short8;
typedef __attribute__((ext_vector_type(4))) unsigned short ushort4v;

__device__ __forceinline__ unsigned short rne_bf16(float f) {
  unsigned int u = __builtin_bit_cast(unsigned int, f);
  u += 0x7FFFu + ((u >> 16) & 1u);
  return (unsigned short)(u >> 16);
}

__device__ __forceinline__ void async16(void* lds, const void* g) {
  __builtin_amdgcn_global_load_lds(
      (const __attribute__((address_space(1))) void*)g,
      (__attribute__((address_space(3))) void*)lds, 16, 0, 0);
}

__device__ __forceinline__ f32x4 mfma16(short8 a, short8 b, f32x4 c) {
  return __builtin_amdgcn_mfma_f32_16x16x32_bf16(a, b, c, 0, 0, 0);
}

// ---------------- f32 -> bf16 cast (vectorized, grid-stride) ----------------
__global__ __launch_bounds__(256) void cast_k(const float* __restrict__ in,
                                              unsigned short* __restrict__ out,
                                              int n4) {
  int stride = gridDim.x * 256;
  for (int i = blockIdx.x * 256 + threadIdx.x; i < n4; i += stride) {
    float4 v = ((const float4*)in)[i];
    ushort4v o = {rne_bf16(v.x), rne_bf16(v.y), rne_bf16(v.z), rne_bf16(v.w)};
    ((ushort4v*)out)[i] = o;
  }
}

// ============ 256x256-tile GEMM: C = A @ B^T (bf16 in, K%64==0, K>=128) ======
// R4-proven version (268us, 0 bank conflicts): 16x16x32 MFMA, 8 waves (2Mx4N),
// 4 rotating 32KB LDS regions; phase P stages region P+3; per-phase counted
// vmcnt(4); reads at head of consuming phase (after barrier); bf double-buffer.
// MODE 0: QKV proj -> bf16 head-transposed dst[(b*16+h)][i][tok], *scale
// MODE 3: out proj -> f32 outF[m*4096+n] + bias[n]
template <int MODE>
__global__ __launch_bounds__(512, 2) void gemm256(const unsigned short* __restrict__ A,
                                                  const unsigned short* __restrict__ B,
                                                  float* __restrict__ outF,
                                                  unsigned short* __restrict__ outB,
                                                  const float* __restrict__ bias,
                                                  int K, int lda, int ldb,
                                                  float scale, int gx) {
  __shared__ unsigned short lds[65536];  // 128 KiB
  const int tid = threadIdx.x;
  const int lane = tid & 63;
  const int wid = tid >> 6;
  const int wm = wid >> 2;  // 0..1 -> 128 rows each
  const int wn = wid & 3;   // 0..3 -> 64 cols each
  int lin = blockIdx.x;
  lin = (lin & 7) * (gridDim.x >> 3) + (lin >> 3);  // XCD swizzle (grid%8==0)
  const int bx = lin % gx;
  const int by = lin / gx;
  const int m0 = by * 256, n0 = bx * 256;
  const int NT = K >> 6;

  // staging: thread t covers LDS slot p = tid (+512): row=p>>2, chunk=p&3
  const int gsw8 = (((tid & 3) ^ ((tid >> 3) & 3))) * 8;  // pre-swizzled col
  const unsigned short* gA = A + (size_t)(m0 + (tid >> 2)) * lda + gsw8;
  const unsigned short* gB = B + (size_t)(n0 + (tid >> 2)) * ldb + gsw8;
  const size_t astep = (size_t)128 * lda;
  const size_t bstep = (size_t)128 * ldb;
  unsigned short* ld0 = &lds[tid * 8];

#define STG(Q) do { \
    const int kt_ = ((Q) >> 1) * 64 + ((Q) & 1) * 32; \
    const int off_ = (((Q) >> 1) & 1) * 32768 + ((Q) & 1) * 8192; \
    const unsigned short* sA_ = gA + kt_; \
    unsigned short* dA_ = ld0 + off_; \
    async16(dA_, sA_); async16(dA_ + 4096, sA_ + astep); \
    const unsigned short* sB_ = gB + kt_; \
    unsigned short* dB_ = ld0 + 16384 + off_; \
    async16(dB_, sB_); async16(dB_ + 4096, sB_ + bstep); } while (0)

  // ds_read addresses (swizzled chunk; conflict-free)
  const int rl = lane & 15;
  const int ch = (lane >> 4) ^ ((rl >> 1) & 3);
  const int aidx = wm * 4096 + rl * 32 + ch * 8;           // + base + r*512
  const int bidx = 16384 + wn * 2048 + rl * 32 + ch * 8;   // + base + s*512

  short8 af[8], bf0[4], bf1[4];
#define READ_A(base) do { \
    _Pragma("unroll") \
    for (int r_ = 0; r_ < 8; ++r_) af[r_] = *(const short8*)&lds[(base) + aidx + r_ * 512]; \
  } while (0)
#define READ_B(base, dst) do { \
    _Pragma("unroll") \
    for (int s_ = 0; s_ < 4; ++s_) dst[s_] = *(const short8*)&lds[(base) + bidx + s_ * 512]; \
  } while (0)

  f32x4 acc[8][4];
#pragma unroll
  for (int r = 0; r < 8; ++r)
#pragma unroll
    for (int s = 0; s < 4; ++s) acc[r][s] = (f32x4){0.f, 0.f, 0.f, 0.f};

#define MFMA32(bfX) do { \
    __builtin_amdgcn_s_setprio(1); \
    _Pragma("unroll") \
    for (int r_ = 0; r_ < 8; ++r_) \
      _Pragma("unroll") \
      for (int s_ = 0; s_ < 4; ++s_) acc[r_][s_] = mfma16(af[r_], bfX[s_], acc[r_][s_]); \
    __builtin_amdgcn_s_setprio(0); \
  } while (0)

  // ---- prologue: stage phases 0,1,2; retire 0,1; publish; prefetch bf(ph0)
  STG(0); STG(1); STG(2);
  asm volatile("s_waitcnt vmcnt(4)" ::: "memory");
  __builtin_amdgcn_s_barrier();
  READ_B(0, bf0);

  for (int t = 0; t < NT; ++t) {
    const int bb = (t & 1) * 32768;
    // ---- phase A (P=2t, kh0): consume bf0, prefetch bf1
    READ_A(bb);
    READ_B(bb + 8192, bf1);            // ph 2t+1 (same tile, staged with it)
    if (t + 1 < NT) STG(2 * t + 3);    // tile t+1, kh1
    __builtin_amdgcn_sched_barrier(0);
    MFMA32(bf0);
    if (t + 1 < NT) asm volatile("s_waitcnt vmcnt(4)" ::: "memory");
    else            asm volatile("s_waitcnt vmcnt(0)" ::: "memory");
    __builtin_amdgcn_s_barrier();
    // ---- phase B (P=2t+1, kh1): consume bf1, prefetch bf0
    READ_A(bb + 8192);
    if (t + 1 < NT) {
      READ_B(((t + 1) & 1) * 32768, bf0);  // ph 2t+2
      if (t + 2 < NT) STG(2 * t + 4);      // tile t+2, kh0
    }
    __builtin_amdgcn_sched_barrier(0);
    MFMA32(bf1);
    if (t + 1 < NT) {
      if (t + 2 < NT) asm volatile("s_waitcnt vmcnt(4)" ::: "memory");
      else            asm volatile("s_waitcnt vmcnt(0)" ::: "memory");
      __builtin_amdgcn_s_barrier();
    }
  }
#undef STG
#undef READ_A
#undef READ_B
#undef MFMA32

  // ---- epilogue: C frag col = lane&15, row = (lane>>4)*4 + j
  const int fcol = lane & 15;
  const int frow = (lane >> 4) * 4;
#pragma unroll
  for (int r = 0; r < 8; ++r) {
#pragma unroll
    for (int s = 0; s < 4; ++s) {
      f32x4 v = acc[r][s];
      const int m = m0 + wm * 128 + r * 16 + frow;
      const int n = n0 + wn * 64 + s * 16 + fcol;
      if (MODE == 0) {
        ushort4v p;
#pragma unroll
        for (int j = 0; j < 4; ++j) p[j] = rne_bf16(v[j] * scale);
        size_t d = ((size_t)((m >> 8) * 16 + (n >> 8))) * 65536 +
                   (size_t)(n & 255) * 256 + (m & 255);
        *(ushort4v*)&outB[d] = p;
      } else {
        float bv = bias[n];
#pragma unroll
        for (int j = 0; j < 4; ++j) outF[(size_t)(m + j) * 4096 + n] = v[j] + bv;
      }
    }
  }
}

// ============ fused per-head attention: S = Qt@Kt^T, softmax, out = P@Vt^T ===
// Block: 64 S-rows x 256 cols, 4 waves (2M x 2N), one head (blockIdx.y).
// Phase 1: S-GEMM (K=256, simple 2-barrier staging) -> acc.
// Phase 2: cross-wave softmax via LDS red arrays; write attn f32 to outA;
//          write P bf16 into LDS Pbuf[64][268] (stride 268 -> write groups hit
//          disjoint 8-bank spans; A-reads ~2-way which is free).
// Phase 3: PV over 8 V-tiles (256x32), double-buffered, counted vmcnt(4);
//          out bf16 -> x-layout. LDS total ~67KB -> 2 blocks/CU.
__global__ __launch_bounds__(256) void attn_fused(const unsigned short* __restrict__ Qt,
                                                  const unsigned short* __restrict__ Kt,
                                                  const unsigned short* __restrict__ Vt,
                                                  float* __restrict__ outA,
                                                  unsigned short* __restrict__ outXb) {
  __shared__ unsigned short sh[34560];
  // shorts layout: Ash [0,2048) | Bsh [2048,10240) | V0 [0,8192) V1 [8192,16384)
  // Pbuf [16384, 16384+64*268) | redM/redS floats at [33536..)
  const int tid = threadIdx.x;
  const int lane = tid & 63;
  const int wid = tid >> 6;
  const int z = blockIdx.y;
  const int m0 = blockIdx.x * 64;
  const int wm = wid >> 1;   // 0..1 -> 32 rows
  const int wn = wid & 1;    // 0..1 -> 128 cols
  const int fcol = lane & 15;
  const int kslot = (lane >> 4) * 8;
  const int frow = (lane >> 4) * 4;

  const unsigned short* Qh = Qt + (size_t)z * 65536;
  const unsigned short* Kh = Kt + (size_t)z * 65536;
  const unsigned short* Vh = Vt + (size_t)z * 65536;
  float* redM = (float*)&sh[33536];  // [64][2]
  float* redS = redM + 128;          // [64][2]

  f32x4 acc[2][8];
#pragma unroll
  for (int r = 0; r < 2; ++r)
#pragma unroll
    for (int s = 0; s < 8; ++s) acc[r][s] = (f32x4){0.f, 0.f, 0.f, 0.f};

  // ---- phase 1: S = Qt[m0..m0+64) @ Kh^T, K = 256
  {
    const int arow = tid >> 2;
    const int acol = (tid & 3) * 8;
    const unsigned short* gQ = Qh + (size_t)(m0 + arow) * 256 + acol;
    const unsigned short* gK = Kh + (size_t)arow * 256 + acol;
    unsigned short* lA = &sh[tid * 8];
    unsigned short* lB = &sh[2048 + tid * 8];

    for (int kt = 0; kt < 256; kt += 32) {
      __syncthreads();
      async16(lA, gQ + kt);
      async16(lB, gK + kt);
      async16(lB + 2048, gK + (size_t)64 * 256 + kt);
      async16(lB + 4096, gK + (size_t)128 * 256 + kt);
      async16(lB + 6144, gK + (size_t)192 * 256 + kt);
      __syncthreads();

      short8 a[2], b[8];
#pragma unroll
      for (int r = 0; r < 2; ++r)
        a[r] = *(const short8*)&sh[(wm * 32 + r * 16 + fcol) * 32 + kslot];
#pragma unroll
      for (int s = 0; s < 8; ++s)
        b[s] = *(const short8*)&sh[2048 + (wn * 128 + s * 16 + fcol) * 32 + kslot];
#pragma unroll
      for (int r = 0; r < 2; ++r)
#pragma unroll
        for (int s = 0; s < 8; ++s)
          acc[r][s] = mfma16(a[r], b[s], acc[r][s]);
    }
  }
  __syncthreads();

  // ---- phase 2: softmax (rows), write outA f32 + Pbuf bf16
#pragma unroll
  for (int r = 0; r < 2; ++r) {
#pragma unroll
    for (int j = 0; j < 4; ++j) {
      float m = acc[r][0][j];
#pragma unroll
      for (int s = 1; s < 8; ++s) m = fmaxf(m, acc[r][s][j]);
#pragma unroll
      for (int off = 1; off < 16; off <<= 1) m = fmaxf(m, __shfl_xor(m, off, 64));
      if (fcol == 0) redM[(wm * 32 + r * 16 + frow + j) * 2 + wn] = m;
    }
  }
  __syncthreads();
#pragma unroll
  for (int r = 0; r < 2; ++r) {
#pragma unroll
    for (int j = 0; j < 4; ++j) {
      const int rl = wm * 32 + r * 16 + frow + j;
      const float m = fmaxf(redM[rl * 2 + 0], redM[rl * 2 + 1]);
      float sum = 0.f;
#pragma unroll
      for (int s = 0; s < 8; ++s) {
        float e = __expf(acc[r][s][j] - m);
        acc[r][s][j] = e;
        sum += e;
      }
#pragma unroll
      for (int off = 1; off < 16; off <<= 1) sum += __shfl_xor(sum, off, 64);
      if (fcol == 0) redS[rl * 2 + wn] = sum;
    }
  }
  __syncthreads();
#pragma unroll
  for (int r = 0; r < 2; ++r) {
#pragma unroll
    for (int j = 0; j < 4; ++j) {
      const int rl = wm * 32 + r * 16 + frow + j;
      const float inv = 1.0f / (redS[rl * 2 + 0] + redS[rl * 2 + 1]);
      const size_t rowo = (size_t)z * 65536 + (size_t)(m0 + rl) * 256;
#pragma unroll
      for (int s = 0; s < 8; ++s) {
        const int col = wn * 128 + s * 16 + fcol;
        const float p = acc[r][s][j] * inv;
        outA[rowo + col] = p;
        sh[16384 + rl * 268 + col] = rne_bf16(p);
      }
    }
  }
  __syncthreads();

  // ---- phase 3: out = P @ Vh^T (K = 256 over 8 tiles of 32, dbuf)
  const unsigned short* gV = Vh + (size_t)(tid >> 2) * 256 + (tid & 3) * 8;
#define STGV(kt, vb) do { \
    _Pragma("unroll") \
    for (int k_ = 0; k_ < 4; ++k_) \
      async16(&sh[(vb) + tid * 8 + k_ * 2048], \
              gV + (size_t)k_ * 64 * 256 + (kt) * 32); } while (0)

  STGV(0, 0); STGV(1, 8192);
  asm volatile("s_waitcnt vmcnt(4)" ::: "memory");
  __builtin_amdgcn_s_barrier();

  f32x4 acc2[2][8];
#pragma unroll
  for (int r = 0; r < 2; ++r)
#pragma unroll
    for (int s = 0; s < 8; ++s) acc2[r][s] = (f32x4){0.f, 0.f, 0.f, 0.f};

  for (int kt = 0; kt < 8; ++kt) {
    const int vb = (kt & 1) * 8192;
    short8 a2[2], b2[8];
#pragma unroll
    for (int r = 0; r < 2; ++r)
      a2[r] = *(const short8*)&sh[16384 + (wm * 32 + r * 16 + fcol) * 268 + kt * 32 + kslot];
#pragma unroll
    for (int s = 0; s < 8; ++s)
      b2[s] = *(const short8*)&sh[vb + (wn * 128 + s * 16 + fcol) * 32 + kslot];
#pragma unroll
    for (int r = 0; r < 2; ++r)
#pragma unroll
      for (int s = 0; s < 8; ++s)
        acc2[r][s] = mfma16(a2[r], b2[s], acc2[r][s]);
    __builtin_amdgcn_s_barrier();      // all waves done reading Vsh[vb]
    if (kt + 2 < 8) {
      STGV(kt + 2, vb);
      asm volatile("s_waitcnt vmcnt(4)" ::: "memory");
    } else {
      asm volatile("s_waitcnt vmcnt(0)" ::: "memory");
    }
    __builtin_amdgcn_s_barrier();
  }
#undef STGV

  // ---- epilogue: x-layout bf16: dst = ((b*256 + i)*4096) + h*256 + c
#pragma unroll
  for (int r = 0; r < 2; ++r) {
#pragma unroll
    for (int s = 0; s < 8; ++s) {
      f32x4 v = acc2[r][s];
      const int i0 = m0 + wm * 32 + r * 16 + frow;
      const int c = wn * 128 + s * 16 + fcol;
#pragma unroll
      for (int j = 0; j < 4; ++j) {
        size_t d = ((size_t)((z >> 4) * 256 + i0 + j)) * 4096 + (z & 15) * 256 + c;
        outXb[d] = rne_bf16(v[j]);
      }
    }
  }
}

// -----------------------------------------------------------------------------
extern "C" void kernel_launch(void* const* d_in, const int* in_sizes, int n_in,
                              void* d_out, int out_size, void* d_ws, size_t ws_size,
                              hipStream_t stream) {
  const float* x1 = (const float*)d_in[0];
  const float* x2 = (const float*)d_in[1];
  const float* Wq = (const float*)d_in[2];
  const float* Wk = (const float*)d_in[3];
  const float* Wv = (const float*)d_in[4];
  const float* Wp = (const float*)d_in[5];
  const float* bp = (const float*)d_in[6];

  float* outX = (float*)d_out;                   // x: [8192,4096] f32
  float* outA = outX + (size_t)33554432;         // attn: [512,256,256] f32

  unsigned short* Qt  = (unsigned short*)d_ws;   // [512][256][256] head-transposed
  unsigned short* Kt  = Qt + 33554432;
  unsigned short* Vt  = Kt + 33554432;
  unsigned short* x1b = Vt + 33554432;           // x1 bf16
  unsigned short* x2b = x1b + 33554432;          // x2 bf16; later out_x bf16
  unsigned short* Wb  = x2b + 33554432;          // current weight bf16 [4096,4096]

  const float SCALE = 0.0625f;  // 256^-0.5

  cast_k<<<2048, 256, 0, stream>>>(x1, x1b, 8388608);
  cast_k<<<2048, 256, 0, stream>>>(x2, x2b, 8388608);

  // Q = (x1 @ Wq^T) * SCALE -> Qt[b,h,i,tok]
  cast_k<<<2048, 256, 0, stream>>>(Wq, Wb, 4194304);
  gemm256<0><<<512, 512, 0, stream>>>(x1b, Wb, nullptr, Qt, nullptr,
                                      4096, 4096, 4096, SCALE, 16);
  // K = x2 @ Wk^T -> Kt
  cast_k<<<2048, 256, 0, stream>>>(Wk, Wb, 4194304);
  gemm256<0><<<512, 512, 0, stream>>>(x2b, Wb, nullptr, Kt, nullptr,
                                      4096, 4096, 4096, 1.0f, 16);
  // V = x2 @ Wv^T -> Vt
  cast_k<<<2048, 256, 0, stream>>>(Wv, Wb, 4194304);
  gemm256<0><<<512, 512, 0, stream>>>(x2b, Wb, nullptr, Vt, nullptr,
                                      4096, 4096, 4096, 1.0f, 16);

  // fused per-head S-GEMM + softmax + PV -> outA f32 + x2b bf16
  attn_fused<<<dim3(4, 512), 256, 0, stream>>>(Qt, Kt, Vt, outA, x2b);

  // x = out @ Wp^T + bp -> d_out
  cast_k<<<2048, 256, 0, stream>>>(Wp, Wb, 4194304);
  gemm256<3><<<512, 512, 0, stream>>>(x2b, Wb, outX, nullptr, bp,
                                      4096, 4096, 4096, 1.0f, 16);
}